// Round 13
// baseline (430.034 us; speedup 1.0000x reference)
//
#include <hip/hip_runtime.h>

#define D_MODEL 2048
#define N_HEADS 16
#define DK 128
#define BATCH 4
#define SEQ 2048
#define BH (BATCH*N_HEADS)   // 64
#define M_TOT (BATCH*SEQ)    // 8192
#define SZ_HEAD ((size_t)BH*SEQ*DK)

typedef _Float16 half8 __attribute__((ext_vector_type(8)));
typedef _Float16 half4 __attribute__((ext_vector_type(4)));
typedef float f32x4 __attribute__((ext_vector_type(4)));
typedef float f32x16 __attribute__((ext_vector_type(16)));

__device__ __forceinline__ void gload_lds16(const void* g, void* l) {
  __builtin_amdgcn_global_load_lds(
      (const __attribute__((address_space(1))) unsigned int*)g,
      (__attribute__((address_space(3))) unsigned int*)l, 16, 0, 0);
}

__device__ __forceinline__ void plswap(unsigned& a, unsigned& b) {
  asm volatile("v_permlane32_swap_b32 %0, %1" : "+v"(a), "+v"(b));
}

#define BARR __builtin_amdgcn_s_barrier()

// ---------------- fused converts: x, 4 weights, rope table ----------------
__global__ void cvt_all(const float* __restrict__ x,
                        const float* __restrict__ w0, const float* __restrict__ w1,
                        const float* __restrict__ w2, const float* __restrict__ w3,
                        _Float16* __restrict__ xh, _Float16* __restrict__ wh,
                        const int* __restrict__ pos, float2* __restrict__ tab) {
  int i = blockIdx.x * blockDim.x + threadIdx.x;
  int stride = gridDim.x * blockDim.x;
  const int NX = 1 << 21;       // x chunks of 8 f32
  const int NW = 1 << 21;       // weight chunks
  const int totalAll = NX + NW + SEQ * 64;
  for (; i < totalAll; i += stride) {
    if (i < NX + NW) {
      const float* s;
      _Float16* d;
      if (i < NX) { s = x + (size_t)i * 8; d = xh + (size_t)i * 8; }
      else {
        int j = i - NX;
        int which = j >> 19;
        int off = j & ((1 << 19) - 1);
        const float* w = which == 0 ? w0 : which == 1 ? w1 : which == 2 ? w2 : w3;
        s = w + (size_t)off * 8;
        d = wh + (size_t)j * 8;
      }
      const float4* sp = (const float4*)s;
      float4 a = sp[0], b = sp[1];
      half8 h;
      h[0] = (_Float16)a.x; h[1] = (_Float16)a.y; h[2] = (_Float16)a.z; h[3] = (_Float16)a.w;
      h[4] = (_Float16)b.x; h[5] = (_Float16)b.y; h[6] = (_Float16)b.z; h[7] = (_Float16)b.w;
      *(half8*)d = h;
    } else {
      int j = i - NX - NW;
      int s = j >> 6, d2 = j & 63;
      float inv = exp2f(-(float)d2 * (13.287712379549449f / 64.0f));
      float ang = (float)pos[s] * inv;
      tab[j] = make_float2(__cosf(ang), __sinf(ang));
    }
  }
}

// ---------------- 256x256 GEMM, BK=64, counted-vmcnt ledger (T4) ----------------
// LDS slots [par][ks] (16KB): 128 rows x 128B; row r pairs global rows r | r+128 (64B each),
// XOR-swizzled by (r&7)<<4. Read addr = invariant reg + par*32768 + imm.
// Per tile: {reads ks0 (12 b128); stage ks0(t+1); c1; c2; vmcnt(4)+bar;
//            reads ks1; stage ks1(t+1); c3; c4; vmcnt(4)+bar}.
// Each wait targets the 4-OLDEST in-flight loads (issued one full tile earlier);
// 4 newest always remain in flight -> no drain in steady state.
// EPI: 2 = f32 row-major out; 3 = fused QKV (Q/K roped via tab, V transposed)
template <int EPI>
__global__ __launch_bounds__(512, 2) void gemm8p(const _Float16* __restrict__ A,
                                                 const _Float16* __restrict__ Bt,
                                                 void* __restrict__ Cout,
                                                 const float2* __restrict__ tab,
                                                 int N, int K) {
  __shared__ char lds[131072]; // A slots [par][ks] @0; B @65536

  const int tid = threadIdx.x;
  const int lane = tid & 63;
  const int w = tid >> 6;
  const int wr = w >> 2, wc = w & 3;
  const int lr = lane & 15, lg = lane >> 4;

  const int nwg = gridDim.x;
  const int cpx = nwg >> 3;
  const int wgid = (blockIdx.x & 7) * cpx + (blockIdx.x >> 3);
  const int nby = M_TOT / 256;
  const int by = wgid % nby, bx = wgid / nby;
  const int m0 = by * 256, n0 = bx * 256;

  const int T = K >> 6;
  const size_t Kb = (size_t)K * 2;
  const char* Ab = (const char*)A + (size_t)m0 * Kb;
  const char* Bb = (const char*)Bt + (size_t)n0 * Kb;

  // loop-invariant per-lane read offsets
  const unsigned xr = (unsigned)((lr & 7) << 4);
  const unsigned aoff = (unsigned)(lr * 128) + (((unsigned)(wr * 64 + lg * 16)) ^ xr);
  const unsigned boff = 65536u + (unsigned)((wc & 1) * 8192) + (unsigned)(lr * 128) +
                        (((unsigned)((wc >> 1) * 64 + lg * 16)) ^ xr);

  // loop-invariant staging offsets
  size_t gso[2];
  unsigned ldo[2];
#pragma unroll
  for (int j = 0; j < 2; ++j) {
    unsigned o = (unsigned)(j * 512 + tid) * 16;
    unsigned row = o >> 7;
    unsigned u = (o & 127u) ^ ((row & 7u) << 4);
    gso[j] = (size_t)(row + ((u >> 6) << 7)) * Kb + (u & 63u);
    ldo[j] = o;
  }

  f32x4 acc[8][4] = {};

  auto stU = [&](int tt, int ks, bool isB) {
    unsigned dst = (isB ? 65536u : 0u) + (unsigned)((tt & 1) * 32768 + ks * 16384);
    const char* src = (isB ? Bb : Ab) + (size_t)tt * 128 + ks * 64;
    gload_lds16(src + gso[0], lds + dst + ldo[0]);
    gload_lds16(src + gso[1], lds + dst + ldo[1]);
  };

  // prologue: tile 0 all 4 units; wait only for the ks0 pair (oldest 4)
  stU(0, 0, false); stU(0, 0, true);
  stU(0, 1, false); stU(0, 1, true);
  asm volatile("s_waitcnt vmcnt(4)" ::: "memory");
  BARR;

  for (int t = 0; t < T; ++t) {
    const unsigned pa = aoff + (unsigned)((t & 1) * 32768);
    const unsigned pb = boff + (unsigned)((t & 1) * 32768);
    const bool more = (t + 1 < T);
    half8 b0[4], a0[4], a1[4];

    // ---- ks0 half: reads + stage ks0(t+1) ----
#pragma unroll
    for (int n = 0; n < 4; ++n) b0[n] = *(const half8*)(lds + pb + n * 2048);
#pragma unroll
    for (int m = 0; m < 4; ++m) a0[m] = *(const half8*)(lds + pa + m * 2048);
#pragma unroll
    for (int m = 0; m < 4; ++m) a1[m] = *(const half8*)(lds + pa + (4 + m) * 2048);
    if (more) { stU(t + 1, 0, false); stU(t + 1, 0, true); }

    __builtin_amdgcn_s_setprio(1);
#pragma unroll
    for (int m = 0; m < 4; ++m)
#pragma unroll
      for (int n = 0; n < 4; ++n)
        acc[m][n] = __builtin_amdgcn_mfma_f32_16x16x32_f16(a0[m], b0[n], acc[m][n], 0, 0, 0);
    __builtin_amdgcn_s_setprio(0);
    __builtin_amdgcn_s_setprio(1);
#pragma unroll
    for (int m = 0; m < 4; ++m)
#pragma unroll
      for (int n = 0; n < 4; ++n)
        acc[4 + m][n] = __builtin_amdgcn_mfma_f32_16x16x32_f16(a1[m], b0[n], acc[4 + m][n], 0, 0, 0);
    __builtin_amdgcn_s_setprio(0);

    // mid wait: ks1(t) units are the 4 oldest in flight (issued mid of t-1)
    if (more) { asm volatile("s_waitcnt vmcnt(4)" ::: "memory"); }
    else      { asm volatile("s_waitcnt vmcnt(0)" ::: "memory"); }
    BARR;

    // ---- ks1 half: reads + stage ks1(t+1) ----
#pragma unroll
    for (int n = 0; n < 4; ++n) b0[n] = *(const half8*)(lds + pb + 16384 + n * 2048);
#pragma unroll
    for (int m = 0; m < 4; ++m) a0[m] = *(const half8*)(lds + pa + 16384 + m * 2048);
#pragma unroll
    for (int m = 0; m < 4; ++m) a1[m] = *(const half8*)(lds + pa + 16384 + (4 + m) * 2048);
    if (more) { stU(t + 1, 1, false); stU(t + 1, 1, true); }

    __builtin_amdgcn_s_setprio(1);
#pragma unroll
    for (int m = 0; m < 4; ++m)
#pragma unroll
      for (int n = 0; n < 4; ++n)
        acc[m][n] = __builtin_amdgcn_mfma_f32_16x16x32_f16(a0[m], b0[n], acc[m][n], 0, 0, 0);
    __builtin_amdgcn_s_setprio(0);
    __builtin_amdgcn_s_setprio(1);
#pragma unroll
    for (int m = 0; m < 4; ++m)
#pragma unroll
      for (int n = 0; n < 4; ++n)
        acc[4 + m][n] = __builtin_amdgcn_mfma_f32_16x16x32_f16(a1[m], b0[n], acc[4 + m][n], 0, 0, 0);
    __builtin_amdgcn_s_setprio(0);

    // end wait: ks0(t+1) units are the 4 oldest in flight
    if (more) {
      asm volatile("s_waitcnt vmcnt(4)" ::: "memory");
      BARR;
    }
  }

  // ---------------- epilogue ----------------
  if (EPI == 3) {
    const int which = n0 >> 11; // 0=Q,1=K,2=V
#pragma unroll
    for (int mf = 0; mf < 8; ++mf) {
      int row0 = m0 + wr * 128 + mf * 16 + lg * 4;
      int b = row0 >> 11;
#pragma unroll
      for (int nf = 0; nf < 4; ++nf) {
        int col = n0 + wc * 64 + nf * 16 + lr;
        int h = (col >> 7) & 15, d = col & 127;
        if (which < 2) {
          _Float16* O = (_Float16*)Cout + (size_t)which * SZ_HEAD;
          int d2 = d >> 1;
#pragma unroll
          for (int r = 0; r < 4; ++r) {
            int s = (row0 + r) & (SEQ - 1);
            float2 cs = tab[(s << 6) + d2];
            float v = acc[mf][nf][r];
            float p = __shfl_xor(v, 1);
            v = (lr & 1) ? fmaf(v, cs.x, p * cs.y) : fmaf(v, cs.x, -p * cs.y);
            O[((size_t)(b * N_HEADS + h) * SEQ + s) * DK + d] = (_Float16)v;
          }
        } else {
          _Float16* O = (_Float16*)Cout + 2 * SZ_HEAD;
          int s = row0 & (SEQ - 1);
          half4 v;
          v[0] = (_Float16)acc[mf][nf][0]; v[1] = (_Float16)acc[mf][nf][1];
          v[2] = (_Float16)acc[mf][nf][2]; v[3] = (_Float16)acc[mf][nf][3];
          *(half4*)&O[((size_t)(b * N_HEADS + h) * DK + d) * SEQ + s] = v;
        }
      }
    }
  } else {
    float* O = (float*)Cout;
#pragma unroll
    for (int mf = 0; mf < 8; ++mf) {
      int row0 = m0 + wr * 128 + mf * 16 + lg * 4;
#pragma unroll
      for (int nf = 0; nf < 4; ++nf) {
        int col = n0 + wc * 64 + nf * 16 + lr;
#pragma unroll
        for (int r = 0; r < 4; ++r)
          O[(size_t)(row0 + r) * N + col] = acc[mf][nf][r];
      }
    }
  }
}

// ---------------- causal flash attention (swapped-operand 32x32) ----------------
__global__ __launch_bounds__(512, 2) void attn_kernel(const _Float16* __restrict__ Q,
                                                      const _Float16* __restrict__ Kg,
                                                      const _Float16* __restrict__ Vt,
                                                      _Float16* __restrict__ ctx) {
  __shared__ char smem[65536];

  const int tid = threadIdx.x, lane = tid & 63, w = tid >> 6;
  const int l31 = lane & 31, hi = lane >> 5;
  const int bh = blockIdx.x & (BH - 1);
  const int qt = (SEQ / 256) - 1 - (blockIdx.x >> 6); // heavy-first
  const int q0 = qt * 256;
  const int qw = q0 + w * 32;
  const int qrow = qw + l31;
  const int nt = (q0 + 256) / 64;

  const char* Kgb = (const char*)(Kg + (size_t)bh * SEQ * DK);
  const char* Vgb = (const char*)(Vt + (size_t)bh * DK * SEQ);

  half8 qf[8];
  {
    const _Float16* qp = Q + ((size_t)bh * SEQ + qrow) * DK + hi * 8;
    const _Float16 sc = (_Float16)0.08838834764831845f;
#pragma unroll
    for (int d = 0; d < 8; ++d) {
      half8 t = *(const half8*)(qp + d * 16);
#pragma unroll
      for (int j = 0; j < 8; ++j) t[j] = t[j] * sc;
      qf[d] = t;
    }
  }

  f32x16 oa[4] = {};
  float m = -3.0e38f, lsum = 0.f;

  auto stage = [&](int t, int buf) {
    char* Kd = smem + buf * 16384;
    char* Vd = smem + 32768 + buf * 16384;
#pragma unroll
    for (int it = 0; it < 2; ++it) {
      int id = it * 512 + tid;
      {
        int row = id >> 4, cc = id & 15;
        int colb = (cc << 4) ^ ((row & 7) << 4);
        gload_lds16(Kgb + (size_t)(t * 64 + row) * 256 + colb, Kd + id * 16);
      }
      {
        int row = id >> 3, cc = id & 7;
        int colb = (cc << 4) ^ ((row & 7) << 4);
        gload_lds16(Vgb + (size_t)row * (SEQ * 2) + (size_t)t * 128 + colb, Vd + id * 16);
      }
    }
  };

  stage(0, 0);
  asm volatile("s_waitcnt vmcnt(0)" ::: "memory");
  __syncthreads();

  int cur = 0;
  for (int t = 0; t < nt; ++t) {
    if (t + 1 < nt) stage(t + 1, cur ^ 1);

    const bool active = (t * 64 <= qw + 31);
    if (active) {
      const char* Kc = smem + cur * 16384;
      const char* Vc = smem + 32768 + cur * 16384;

      f32x16 sA = {}, sB = {};
      __builtin_amdgcn_s_setprio(1);
#pragma unroll
      for (int d = 0; d < 8; ++d) {
        int cb = d * 32 + hi * 16;
        half8 kA = *(const half8*)(Kc + l31 * 256 + (cb ^ ((l31 & 7) << 4)));
        half8 kB = *(const half8*)(Kc + (l31 + 32) * 256 + (cb ^ ((l31 & 7) << 4)));
        sA = __builtin_amdgcn_mfma_f32_32x32x16_f16(kA, qf[d], sA, 0, 0, 0);
        sB = __builtin_amdgcn_mfma_f32_32x32x16_f16(kB, qf[d], sB, 0, 0, 0);
      }
      __builtin_amdgcn_s_setprio(0);

      if (t * 64 + 63 > qw) {
#pragma unroll
        for (int r = 0; r < 16; ++r) {
          int k = t * 64 + (r & 3) + 8 * (r >> 2) + 4 * hi;
          if (k > qrow) sA[r] = -3.0e38f;
          if (k + 32 > qrow) sB[r] = -3.0e38f;
        }
      }

      float tm = -3.0e38f;
#pragma unroll
      for (int r = 0; r < 16; ++r) tm = fmaxf(tm, fmaxf(sA[r], sB[r]));
      tm = fmaxf(tm, __shfl_xor(tm, 32));

      if (__any(tm > m + 8.0f)) {
        float mnew = fmaxf(m, tm);
        float sf = __expf(m - mnew);
        m = mnew;
        lsum *= sf;
#pragma unroll
        for (int db = 0; db < 4; ++db)
#pragma unroll
          for (int r = 0; r < 16; ++r) oa[db][r] *= sf;
      }

      float ps = 0.f;
      unsigned wa[8], wb[8];
#pragma unroll
      for (int i = 0; i < 8; ++i) {
        float a0 = __expf(sA[2 * i] - m), a1 = __expf(sA[2 * i + 1] - m);
        float b0 = __expf(sB[2 * i] - m), b1 = __expf(sB[2 * i + 1] - m);
        ps += a0 + a1 + b0 + b1;
        wa[i] = __builtin_bit_cast(unsigned, __builtin_amdgcn_cvt_pkrtz(a0, a1));
        wb[i] = __builtin_bit_cast(unsigned, __builtin_amdgcn_cvt_pkrtz(b0, b1));
      }
      lsum += ps;

      plswap(wa[0], wa[2]); plswap(wa[1], wa[3]); plswap(wa[4], wa[6]); plswap(wa[5], wa[7]);
      plswap(wb[0], wb[2]); plswap(wb[1], wb[3]); plswap(wb[4], wb[6]); plswap(wb[5], wb[7]);

      union { unsigned u[4]; half8 v; } pf[4];
      pf[0].u[0] = wa[0]; pf[0].u[1] = wa[1]; pf[0].u[2] = wa[2]; pf[0].u[3] = wa[3];
      pf[1].u[0] = wa[4]; pf[1].u[1] = wa[5]; pf[1].u[2] = wa[6]; pf[1].u[3] = wa[7];
      pf[2].u[0] = wb[0]; pf[2].u[1] = wb[1]; pf[2].u[2] = wb[2]; pf[2].u[3] = wb[3];
      pf[3].u[0] = wb[4]; pf[3].u[1] = wb[5]; pf[3].u[2] = wb[6]; pf[3].u[3] = wb[7];

      __builtin_amdgcn_s_setprio(1);
#pragma unroll
      for (int kg = 0; kg < 4; ++kg) {
#pragma unroll
        for (int db = 0; db < 4; ++db) {
          int row = db * 32 + l31;
          half8 vf = *(const half8*)(Vc + row * 128 + ((kg * 32 + hi * 16) ^ ((row & 7) << 4)));
          oa[db] = __builtin_amdgcn_mfma_f32_32x32x16_f16(vf, pf[kg].v, oa[db], 0, 0, 0);
        }
      }
      __builtin_amdgcn_s_setprio(0);
    }

    asm volatile("s_waitcnt vmcnt(0)" ::: "memory");
    __syncthreads();
    cur ^= 1;
  }

  __syncthreads();
  float lt = lsum + __shfl_xor(lsum, 32);
  float invl = 1.0f / lt;
  char* Ob = smem + w * 8192;
#pragma unroll
  for (int db = 0; db < 4; ++db)
#pragma unroll
    for (int r = 0; r < 16; ++r) {
      int d = db * 32 + (r & 3) + 8 * (r >> 2) + 4 * hi;
      *(_Float16*)(Ob + l31 * 256 + ((2 * d) ^ ((l31 & 7) << 4))) = (_Float16)(oa[db][r] * invl);
    }
  __builtin_amdgcn_s_waitcnt(0);
  const int b = bh >> 4, h = bh & 15;
#pragma unroll
  for (int i = 0; i < 8; ++i) {
    int cidx = i * 64 + lane;
    int row = cidx >> 4;
    int colb = (cidx & 15) * 16;
    half8 v = *(const half8*)(Ob + row * 256 + (colb ^ ((row & 7) << 4)));
    int s = qw + row;
    *(half8*)(ctx + ((size_t)(b * SEQ + s)) * D_MODEL + h * DK + colb / 2) = v;
  }
}

// ---------------- launch ----------------
extern "C" void kernel_launch(void* const* d_in, const int* in_sizes, int n_in,
                              void* d_out, int out_size, void* d_ws, size_t ws_size,
                              hipStream_t stream) {
  const float* x = (const float*)d_in[0];
  const int* pos = (const int*)d_in[1];
  const float* Wq = (const float*)d_in[2];
  const float* Wk = (const float*)d_in[3];
  const float* Wv = (const float*)d_in[4];
  const float* Wo = (const float*)d_in[5];
  float* out = (float*)d_out;

  const size_t SZ_XH = (size_t)M_TOT * D_MODEL;
  const size_t SZ_W = (size_t)D_MODEL * D_MODEL;

  _Float16* xh = (_Float16*)d_ws;
  _Float16* wqh = xh + SZ_XH;        // Wq,Wk,Wv,Wo contiguous
  _Float16* woh = wqh + 3 * SZ_W;
  _Float16* Qh = woh + SZ_W;
  _Float16* Kh = Qh + SZ_HEAD;
  _Float16* Vth = Kh + SZ_HEAD;
  _Float16* ctx = xh;                 // alias: xh dead after QKV GEMM
  float2* tab = (float2*)d_out;       // first 1MB of out; fully overwritten by O-GEMM

  cvt_all<<<4096, 256, 0, stream>>>(x, Wq, Wk, Wv, Wo, xh, wqh, pos, tab);

  // fused QKV projection: N = 6144, 256x256 tiles -> 32x24 = 768 blocks
  gemm8p<3><<<768, 512, 0, stream>>>(xh, wqh, Qh, tab, 3 * D_MODEL, D_MODEL);

  attn_kernel<<<(SEQ / 256) * BH, 512, 0, stream>>>(Qh, Kh, Vth, ctx);

  // output projection: 32x8 = 256 blocks
  gemm8p<2><<<256, 512, 0, stream>>>(ctx, woh, out, nullptr, D_MODEL, D_MODEL);
}

// Round 14
// 403.586 us; speedup vs baseline: 1.0655x; 1.0655x over previous
//
#include <hip/hip_runtime.h>

#define D_MODEL 2048
#define N_HEADS 16
#define DK 128
#define BATCH 4
#define SEQ 2048
#define BH (BATCH*N_HEADS)   // 64
#define M_TOT (BATCH*SEQ)    // 8192
#define SZ_HEAD ((size_t)BH*SEQ*DK)

typedef _Float16 half8 __attribute__((ext_vector_type(8)));
typedef _Float16 half4 __attribute__((ext_vector_type(4)));
typedef float f32x4 __attribute__((ext_vector_type(4)));
typedef float f32x16 __attribute__((ext_vector_type(16)));

__device__ __forceinline__ void gload_lds16(const void* g, void* l) {
  __builtin_amdgcn_global_load_lds(
      (const __attribute__((address_space(1))) unsigned int*)g,
      (__attribute__((address_space(3))) unsigned int*)l, 16, 0, 0);
}

__device__ __forceinline__ void plswap(unsigned& a, unsigned& b) {
  asm volatile("v_permlane32_swap_b32 %0, %1" : "+v"(a), "+v"(b));
}

#define SBAR __builtin_amdgcn_sched_barrier(0)
#define BARR __builtin_amdgcn_s_barrier()

// ---------------- fused converts: x, 4 weights, rope table ----------------
__global__ void cvt_all(const float* __restrict__ x,
                        const float* __restrict__ w0, const float* __restrict__ w1,
                        const float* __restrict__ w2, const float* __restrict__ w3,
                        _Float16* __restrict__ xh, _Float16* __restrict__ wh,
                        const int* __restrict__ pos, float2* __restrict__ tab) {
  int i = blockIdx.x * blockDim.x + threadIdx.x;
  int stride = gridDim.x * blockDim.x;
  const int NX = 1 << 21;       // x chunks of 8 f32
  const int NW = 1 << 21;       // weight chunks
  const int totalAll = NX + NW + SEQ * 64;
  for (; i < totalAll; i += stride) {
    if (i < NX + NW) {
      const float* s;
      _Float16* d;
      if (i < NX) { s = x + (size_t)i * 8; d = xh + (size_t)i * 8; }
      else {
        int j = i - NX;
        int which = j >> 19;
        int off = j & ((1 << 19) - 1);
        const float* w = which == 0 ? w0 : which == 1 ? w1 : which == 2 ? w2 : w3;
        s = w + (size_t)off * 8;
        d = wh + (size_t)j * 8;
      }
      const float4* sp = (const float4*)s;
      float4 a = sp[0], b = sp[1];
      half8 h;
      h[0] = (_Float16)a.x; h[1] = (_Float16)a.y; h[2] = (_Float16)a.z; h[3] = (_Float16)a.w;
      h[4] = (_Float16)b.x; h[5] = (_Float16)b.y; h[6] = (_Float16)b.z; h[7] = (_Float16)b.w;
      *(half8*)d = h;
    } else {
      int j = i - NX - NW;
      int s = j >> 6, d2 = j & 63;
      float inv = exp2f(-(float)d2 * (13.287712379549449f / 64.0f));
      float ang = (float)pos[s] * inv;
      tab[j] = make_float2(__cosf(ang), __sinf(ang));
    }
  }
}

// ---------------- 256x256 GEMM, BK=64, hoisted-operand pipeline (R10 best) ----------------
// LDS slots [par][ks] (16KB): 128 rows x 128B; row r pairs global rows r | r+128 (64B each),
// XOR-swizzled by (r&7)<<4. Read addr = invariant reg + par*32768 + imm.
// Per tile: hoist {B0,A0-3} and {B1,A'0-3} reads before MFMAs (SBAR-pinned); A4-7 groups
// read under MFMA clusters; 1 barrier + vmcnt(0) per tile.
// EPI: 2 = f32 row-major out; 3 = fused QKV (Q/K roped via tab, V transposed)
template <int EPI>
__global__ __launch_bounds__(512, 2) void gemm8p(const _Float16* __restrict__ A,
                                                 const _Float16* __restrict__ Bt,
                                                 void* __restrict__ Cout,
                                                 const float2* __restrict__ tab,
                                                 int N, int K) {
  __shared__ char lds[131072]; // A slots [par][ks] @0; B @65536

  const int tid = threadIdx.x;
  const int lane = tid & 63;
  const int w = tid >> 6;
  const int wr = w >> 2, wc = w & 3;
  const int lr = lane & 15, lg = lane >> 4;

  const int nwg = gridDim.x;
  const int cpx = nwg >> 3;
  const int wgid = (blockIdx.x & 7) * cpx + (blockIdx.x >> 3);
  const int nby = M_TOT / 256;
  const int by = wgid % nby, bx = wgid / nby;
  const int m0 = by * 256, n0 = bx * 256;

  const int T = K >> 6;
  const size_t Kb = (size_t)K * 2;
  const char* Ab = (const char*)A + (size_t)m0 * Kb;
  const char* Bb = (const char*)Bt + (size_t)n0 * Kb;

  // loop-invariant per-lane read offsets
  const unsigned xr = (unsigned)((lr & 7) << 4);
  const unsigned aoff = (unsigned)(lr * 128) + (((unsigned)(wr * 64 + lg * 16)) ^ xr);
  const unsigned boff = 65536u + (unsigned)((wc & 1) * 8192) + (unsigned)(lr * 128) +
                        (((unsigned)((wc >> 1) * 64 + lg * 16)) ^ xr);

  // loop-invariant staging offsets
  size_t gso[2];
  unsigned ldo[2];
#pragma unroll
  for (int j = 0; j < 2; ++j) {
    unsigned o = (unsigned)(j * 512 + tid) * 16;
    unsigned row = o >> 7;
    unsigned u = (o & 127u) ^ ((row & 7u) << 4);
    gso[j] = (size_t)(row + ((u >> 6) << 7)) * Kb + (u & 63u);
    ldo[j] = o;
  }

  f32x4 acc[8][4] = {};

  auto stU = [&](int tt, int ks, bool isB) {
    unsigned dst = (isB ? 65536u : 0u) + (unsigned)((tt & 1) * 32768 + ks * 16384);
    const char* src = (isB ? Bb : Ab) + (size_t)tt * 128 + ks * 64;
    gload_lds16(src + gso[0], lds + dst + ldo[0]);
    gload_lds16(src + gso[1], lds + dst + ldo[1]);
  };

  // prologue: tile 0 all 4 units
  stU(0, 0, false); stU(0, 1, false); stU(0, 0, true); stU(0, 1, true);
  asm volatile("s_waitcnt vmcnt(0)" ::: "memory");
  BARR;

  for (int t = 0; t < T; ++t) {
    const unsigned pa = aoff + (unsigned)((t & 1) * 32768);
    const unsigned pb = boff + (unsigned)((t & 1) * 32768);
    const bool more = (t + 1 < T);
    half8 b0[4], a0[4], b1[4], a2[4], a1[4], a3[4];

    // ---- hoisted read group 1: ks0 {B, A m0-3} ----
#pragma unroll
    for (int n = 0; n < 4; ++n) b0[n] = *(const half8*)(lds + pb + n * 2048);
#pragma unroll
    for (int m = 0; m < 4; ++m) a0[m] = *(const half8*)(lds + pa + m * 2048);
    SBAR;
    if (more) { stU(t + 1, 0, false); stU(t + 1, 1, false); }
    // ---- hoisted read group 2: ks1 {B, A m0-3} ----
#pragma unroll
    for (int n = 0; n < 4; ++n) b1[n] = *(const half8*)(lds + pb + 16384 + n * 2048);
#pragma unroll
    for (int m = 0; m < 4; ++m) a2[m] = *(const half8*)(lds + pa + 16384 + m * 2048);
    SBAR;

    // ---- MFMA cluster 1: ks0 x m0-3 (a1 reads issue under it) ----
    __builtin_amdgcn_s_setprio(1);
#pragma unroll
    for (int m = 0; m < 4; ++m)
#pragma unroll
      for (int n = 0; n < 4; ++n)
        acc[m][n] = __builtin_amdgcn_mfma_f32_16x16x32_f16(a0[m], b0[n], acc[m][n], 0, 0, 0);
    __builtin_amdgcn_s_setprio(0);
#pragma unroll
    for (int m = 0; m < 4; ++m) a1[m] = *(const half8*)(lds + pa + (4 + m) * 2048);
    if (more) { stU(t + 1, 0, true); stU(t + 1, 1, true); }
    SBAR;

    // ---- MFMA cluster 2: ks0 x m4-7 ----
    __builtin_amdgcn_s_setprio(1);
#pragma unroll
    for (int m = 0; m < 4; ++m)
#pragma unroll
      for (int n = 0; n < 4; ++n)
        acc[4 + m][n] = __builtin_amdgcn_mfma_f32_16x16x32_f16(a1[m], b0[n], acc[4 + m][n], 0, 0, 0);
    __builtin_amdgcn_s_setprio(0);
#pragma unroll
    for (int m = 0; m < 4; ++m) a3[m] = *(const half8*)(lds + pa + 16384 + (4 + m) * 2048);
    SBAR;

    // ---- MFMA cluster 3: ks1 x m0-3 ----
    __builtin_amdgcn_s_setprio(1);
#pragma unroll
    for (int m = 0; m < 4; ++m)
#pragma unroll
      for (int n = 0; n < 4; ++n)
        acc[m][n] = __builtin_amdgcn_mfma_f32_16x16x32_f16(a2[m], b1[n], acc[m][n], 0, 0, 0);
    __builtin_amdgcn_s_setprio(0);

    // ---- MFMA cluster 4: ks1 x m4-7 ----
    __builtin_amdgcn_s_setprio(1);
#pragma unroll
    for (int m = 0; m < 4; ++m)
#pragma unroll
      for (int n = 0; n < 4; ++n)
        acc[4 + m][n] = __builtin_amdgcn_mfma_f32_16x16x32_f16(a3[m], b1[n], acc[4 + m][n], 0, 0, 0);
    __builtin_amdgcn_s_setprio(0);

    // ---- boundary ----
    asm volatile("s_waitcnt vmcnt(0)" ::: "memory");
    BARR;
  }

  // ---------------- epilogue ----------------
  if (EPI == 3) {
    const int which = n0 >> 11; // 0=Q,1=K,2=V
#pragma unroll
    for (int mf = 0; mf < 8; ++mf) {
      int row0 = m0 + wr * 128 + mf * 16 + lg * 4;
      int b = row0 >> 11;
#pragma unroll
      for (int nf = 0; nf < 4; ++nf) {
        int col = n0 + wc * 64 + nf * 16 + lr;
        int h = (col >> 7) & 15, d = col & 127;
        if (which < 2) {
          _Float16* O = (_Float16*)Cout + (size_t)which * SZ_HEAD;
          int d2 = d >> 1;
#pragma unroll
          for (int r = 0; r < 4; ++r) {
            int s = (row0 + r) & (SEQ - 1);
            float2 cs = tab[(s << 6) + d2];
            float v = acc[mf][nf][r];
            float p = __shfl_xor(v, 1);
            v = (lr & 1) ? fmaf(v, cs.x, p * cs.y) : fmaf(v, cs.x, -p * cs.y);
            O[((size_t)(b * N_HEADS + h) * SEQ + s) * DK + d] = (_Float16)v;
          }
        } else {
          _Float16* O = (_Float16*)Cout + 2 * SZ_HEAD;
          int s = row0 & (SEQ - 1);
          half4 v;
          v[0] = (_Float16)acc[mf][nf][0]; v[1] = (_Float16)acc[mf][nf][1];
          v[2] = (_Float16)acc[mf][nf][2]; v[3] = (_Float16)acc[mf][nf][3];
          *(half4*)&O[((size_t)(b * N_HEADS + h) * DK + d) * SEQ + s] = v;
        }
      }
    }
  } else {
    float* O = (float*)Cout;
#pragma unroll
    for (int mf = 0; mf < 8; ++mf) {
      int row0 = m0 + wr * 128 + mf * 16 + lg * 4;
#pragma unroll
      for (int nf = 0; nf < 4; ++nf) {
        int col = n0 + wc * 64 + nf * 16 + lr;
#pragma unroll
        for (int r = 0; r < 4; ++r)
          O[(size_t)(row0 + r) * N + col] = acc[mf][nf][r];
      }
    }
  }
}

// ---------------- causal flash attention (swapped-operand 32x32) ----------------
__global__ __launch_bounds__(512, 2) void attn_kernel(const _Float16* __restrict__ Q,
                                                      const _Float16* __restrict__ Kg,
                                                      const _Float16* __restrict__ Vt,
                                                      _Float16* __restrict__ ctx) {
  __shared__ char smem[65536];

  const int tid = threadIdx.x, lane = tid & 63, w = tid >> 6;
  const int l31 = lane & 31, hi = lane >> 5;
  const int bh = blockIdx.x & (BH - 1);
  const int qt = (SEQ / 256) - 1 - (blockIdx.x >> 6); // heavy-first
  const int q0 = qt * 256;
  const int qw = q0 + w * 32;
  const int qrow = qw + l31;
  const int nt = (q0 + 256) / 64;

  const char* Kgb = (const char*)(Kg + (size_t)bh * SEQ * DK);
  const char* Vgb = (const char*)(Vt + (size_t)bh * DK * SEQ);

  half8 qf[8];
  {
    const _Float16* qp = Q + ((size_t)bh * SEQ + qrow) * DK + hi * 8;
    const _Float16 sc = (_Float16)0.08838834764831845f;
#pragma unroll
    for (int d = 0; d < 8; ++d) {
      half8 t = *(const half8*)(qp + d * 16);
#pragma unroll
      for (int j = 0; j < 8; ++j) t[j] = t[j] * sc;
      qf[d] = t;
    }
  }

  f32x16 oa[4] = {};
  float m = -3.0e38f, lsum = 0.f;

  auto stage = [&](int t, int buf) {
    char* Kd = smem + buf * 16384;
    char* Vd = smem + 32768 + buf * 16384;
#pragma unroll
    for (int it = 0; it < 2; ++it) {
      int id = it * 512 + tid;
      {
        int row = id >> 4, cc = id & 15;
        int colb = (cc << 4) ^ ((row & 7) << 4);
        gload_lds16(Kgb + (size_t)(t * 64 + row) * 256 + colb, Kd + id * 16);
      }
      {
        int row = id >> 3, cc = id & 7;
        int colb = (cc << 4) ^ ((row & 7) << 4);
        gload_lds16(Vgb + (size_t)row * (SEQ * 2) + (size_t)t * 128 + colb, Vd + id * 16);
      }
    }
  };

  stage(0, 0);
  asm volatile("s_waitcnt vmcnt(0)" ::: "memory");
  __syncthreads();

  int cur = 0;
  for (int t = 0; t < nt; ++t) {
    if (t + 1 < nt) stage(t + 1, cur ^ 1);

    const bool active = (t * 64 <= qw + 31);
    if (active) {
      const char* Kc = smem + cur * 16384;
      const char* Vc = smem + 32768 + cur * 16384;

      f32x16 sA = {}, sB = {};
      __builtin_amdgcn_s_setprio(1);
#pragma unroll
      for (int d = 0; d < 8; ++d) {
        int cb = d * 32 + hi * 16;
        half8 kA = *(const half8*)(Kc + l31 * 256 + (cb ^ ((l31 & 7) << 4)));
        half8 kB = *(const half8*)(Kc + (l31 + 32) * 256 + (cb ^ ((l31 & 7) << 4)));
        sA = __builtin_amdgcn_mfma_f32_32x32x16_f16(kA, qf[d], sA, 0, 0, 0);
        sB = __builtin_amdgcn_mfma_f32_32x32x16_f16(kB, qf[d], sB, 0, 0, 0);
      }
      __builtin_amdgcn_s_setprio(0);

      if (t * 64 + 63 > qw) {
#pragma unroll
        for (int r = 0; r < 16; ++r) {
          int k = t * 64 + (r & 3) + 8 * (r >> 2) + 4 * hi;
          if (k > qrow) sA[r] = -3.0e38f;
          if (k + 32 > qrow) sB[r] = -3.0e38f;
        }
      }

      float tm = -3.0e38f;
#pragma unroll
      for (int r = 0; r < 16; ++r) tm = fmaxf(tm, fmaxf(sA[r], sB[r]));
      tm = fmaxf(tm, __shfl_xor(tm, 32));

      if (__any(tm > m + 8.0f)) {
        float mnew = fmaxf(m, tm);
        float sf = __expf(m - mnew);
        m = mnew;
        lsum *= sf;
#pragma unroll
        for (int db = 0; db < 4; ++db)
#pragma unroll
          for (int r = 0; r < 16; ++r) oa[db][r] *= sf;
      }

      float ps = 0.f;
      unsigned wa[8], wb[8];
#pragma unroll
      for (int i = 0; i < 8; ++i) {
        float a0 = __expf(sA[2 * i] - m), a1 = __expf(sA[2 * i + 1] - m);
        float b0 = __expf(sB[2 * i] - m), b1 = __expf(sB[2 * i + 1] - m);
        ps += a0 + a1 + b0 + b1;
        wa[i] = __builtin_bit_cast(unsigned, __builtin_amdgcn_cvt_pkrtz(a0, a1));
        wb[i] = __builtin_bit_cast(unsigned, __builtin_amdgcn_cvt_pkrtz(b0, b1));
      }
      lsum += ps;

      plswap(wa[0], wa[2]); plswap(wa[1], wa[3]); plswap(wa[4], wa[6]); plswap(wa[5], wa[7]);
      plswap(wb[0], wb[2]); plswap(wb[1], wb[3]); plswap(wb[4], wb[6]); plswap(wb[5], wb[7]);

      union { unsigned u[4]; half8 v; } pf[4];
      pf[0].u[0] = wa[0]; pf[0].u[1] = wa[1]; pf[0].u[2] = wa[2]; pf[0].u[3] = wa[3];
      pf[1].u[0] = wa[4]; pf[1].u[1] = wa[5]; pf[1].u[2] = wa[6]; pf[1].u[3] = wa[7];
      pf[2].u[0] = wb[0]; pf[2].u[1] = wb[1]; pf[2].u[2] = wb[2]; pf[2].u[3] = wb[3];
      pf[3].u[0] = wb[4]; pf[3].u[1] = wb[5]; pf[3].u[2] = wb[6]; pf[3].u[3] = wb[7];

      __builtin_amdgcn_s_setprio(1);
#pragma unroll
      for (int kg = 0; kg < 4; ++kg) {
#pragma unroll
        for (int db = 0; db < 4; ++db) {
          int row = db * 32 + l31;
          half8 vf = *(const half8*)(Vc + row * 128 + ((kg * 32 + hi * 16) ^ ((row & 7) << 4)));
          oa[db] = __builtin_amdgcn_mfma_f32_32x32x16_f16(vf, pf[kg].v, oa[db], 0, 0, 0);
        }
      }
      __builtin_amdgcn_s_setprio(0);
    }

    asm volatile("s_waitcnt vmcnt(0)" ::: "memory");
    __syncthreads();
    cur ^= 1;
  }

  __syncthreads();
  float lt = lsum + __shfl_xor(lsum, 32);
  float invl = 1.0f / lt;
  char* Ob = smem + w * 8192;
#pragma unroll
  for (int db = 0; db < 4; ++db)
#pragma unroll
    for (int r = 0; r < 16; ++r) {
      int d = db * 32 + (r & 3) + 8 * (r >> 2) + 4 * hi;
      *(_Float16*)(Ob + l31 * 256 + ((2 * d) ^ ((l31 & 7) << 4))) = (_Float16)(oa[db][r] * invl);
    }
  __builtin_amdgcn_s_waitcnt(0);
  const int b = bh >> 4, h = bh & 15;
#pragma unroll
  for (int i = 0; i < 8; ++i) {
    int cidx = i * 64 + lane;
    int row = cidx >> 4;
    int colb = (cidx & 15) * 16;
    half8 v = *(const half8*)(Ob + row * 256 + (colb ^ ((row & 7) << 4)));
    int s = qw + row;
    *(half8*)(ctx + ((size_t)(b * SEQ + s)) * D_MODEL + h * DK + colb / 2) = v;
  }
}

// ---------------- launch ----------------
extern "C" void kernel_launch(void* const* d_in, const int* in_sizes, int n_in,
                              void* d_out, int out_size, void* d_ws, size_t ws_size,
                              hipStream_t stream) {
  const float* x = (const float*)d_in[0];
  const int* pos = (const int*)d_in[1];
  const float* Wq = (const float*)d_in[2];
  const float* Wk = (const float*)d_in[3];
  const float* Wv = (const float*)d_in[4];
  const float* Wo = (const float*)d_in[5];
  float* out = (float*)d_out;

  const size_t SZ_XH = (size_t)M_TOT * D_MODEL;
  const size_t SZ_W = (size_t)D_MODEL * D_MODEL;

  _Float16* xh = (_Float16*)d_ws;
  _Float16* wqh = xh + SZ_XH;        // Wq,Wk,Wv,Wo contiguous
  _Float16* woh = wqh + 3 * SZ_W;
  _Float16* Qh = woh + SZ_W;
  _Float16* Kh = Qh + SZ_HEAD;
  _Float16* Vth = Kh + SZ_HEAD;
  _Float16* ctx = xh;                 // alias: xh dead after QKV GEMM
  float2* tab = (float2*)d_out;       // first 1MB of out; fully overwritten by O-GEMM

  cvt_all<<<4096, 256, 0, stream>>>(x, Wq, Wk, Wv, Wo, xh, wqh, pos, tab);

  // fused QKV projection: N = 6144, 256x256 tiles -> 32x24 = 768 blocks
  gemm8p<3><<<768, 512, 0, stream>>>(xh, wqh, Qh, tab, 3 * D_MODEL, D_MODEL);

  attn_kernel<<<(SEQ / 256) * BH, 512, 0, stream>>>(Qh, Kh, Vth, ctx);

  // output projection: 32x8 = 256 blocks
  gemm8p<2><<<256, 512, 0, stream>>>(ctx, woh, out, nullptr, D_MODEL, D_MODEL);
}